// Round 5
// baseline (680.141 us; speedup 1.0000x reference)
//
#include <hip/hip_runtime.h>

typedef unsigned short u16;
typedef unsigned int u32;
typedef short short8 __attribute__((ext_vector_type(8)));
typedef float floatx4 __attribute__((ext_vector_type(4)));

__device__ __forceinline__ float bf2f(u16 x) { return __uint_as_float(((u32)x) << 16); }
__device__ __forceinline__ u16 f2bf(float x) {
    u32 u = __float_as_uint(x);
    u += 0x7fffu + ((u >> 16) & 1u);
    return (u16)(u >> 16);
}
// pack two fp32 -> u32 of 2 bf16 (RNE), single HW instruction
__device__ __forceinline__ u32 cvt_pk_bf16(float lo, float hi) {
    u32 r;
    asm("v_cvt_pk_bf16_f32 %0, %1, %2" : "=v"(r) : "v"(lo), "v"(hi));
    return r;
}

// ---------------- diagnostic: zero the output (fp32) ----------------
__global__ void zero_out_k(float* __restrict__ out, int n) {
    int i = blockIdx.x * 256 + threadIdx.x;
    if (i < n) out[i] = 0.f;
}

// ---------------- weight prepack helper ----------------
// Wf[(kq*DO + n)*8 + j] = bf16(W[(kq*8 + j)*DO + n])   (k = kq*8 + j)
__device__ __forceinline__ void prepack1(const float* W, u16* Wf, int DO, int idx) {
    int j = idx & 7;
    int t = idx >> 3;
    int n = t % DO;
    int kq = t / DO;
    Wf[idx] = f2bf(W[(size_t)(kq * 8 + j) * DO + n]);
}

// ---------------- CSR histogram+rank (+all-3 weight prepack piggyback) ----------------
// Standalone (VGPR ~8): latency-bound random atomics need max waves/CU — do NOT
// fuse with the GEMM (R4 post-mortem: fused occupancy 29% tripled hist time).
__global__ void hist_prepack_k(const int* __restrict__ dst, int* __restrict__ cnt,
                               u16* __restrict__ rank, int E, int N,
                               const float* __restrict__ W1, u16* __restrict__ Wf1,
                               const float* __restrict__ W2, u16* __restrict__ Wf2,
                               const float* __restrict__ W3, u16* __restrict__ Wf3) {
    int e = blockIdx.x * 256 + threadIdx.x;
    if (e < E) {
        int d = dst[e];
        d = d < 0 ? 0 : (d >= N ? N - 1 : d);
        rank[e] = (u16)atomicAdd(&cnt[d], 1);
    }
    const int T1 = 512 * 128, T2 = 128 * 128, T3 = 128 * 64;
    if (e < T1) prepack1(W1, Wf1, 128, e);
    else if (e < T1 + T2) prepack1(W2, Wf2, 128, e - T1);
    else if (e < T1 + T2 + T3) prepack1(W3, Wf3, 64, e - T1 - T2);
}

// ---------------- scans ----------------
// block-level exclusive scan: 16 waves, shfl-scan per wave + cross-wave LDS combine
__global__ void scan1_k(const int* __restrict__ cnt, int* __restrict__ excl,
                        int* __restrict__ aux, int N) {
    __shared__ int wsum[16];
    int t = threadIdx.x;
    int wv = t >> 6, ln = t & 63;
    int i = blockIdx.x * 1024 + t;
    int v = (i < N) ? cnt[i] : 0;
    int s = v;
    for (int off = 1; off < 64; off <<= 1) { int x = __shfl_up(s, off); if (ln >= off) s += x; }
    if (ln == 63) wsum[wv] = s;
    __syncthreads();
    if (wv == 0) {
        int ws = (ln < 16) ? wsum[ln] : 0;
        int ss = ws;
        for (int off = 1; off < 16; off <<= 1) { int x = __shfl_up(ss, off); if (ln >= off) ss += x; }
        if (ln < 16) wsum[ln] = ss - ws;  // exclusive wave offsets
    }
    __syncthreads();
    int base = wsum[wv];
    if (i < N) excl[i] = base + s - v;
    if (t == 1023) aux[blockIdx.x] = base + s;
}

__global__ void scan2_k(int* __restrict__ aux, int nb) {
    int lane = threadIdx.x;  // single block of 64; nb <= 128
    int v0 = (lane < nb) ? aux[lane] : 0;
    int v1 = (lane + 64 < nb) ? aux[lane + 64] : 0;
    int s0 = v0;
    for (int off = 1; off < 64; off <<= 1) { int x = __shfl_up(s0, off); if (lane >= off) s0 += x; }
    int total0 = __shfl(s0, 63);
    int s1 = v1;
    for (int off = 1; off < 64; off <<= 1) { int x = __shfl_up(s1, off); if (lane >= off) s1 += x; }
    if (lane < nb) aux[lane] = s0 - v0;
    if (lane + 64 < nb) aux[lane + 64] = total0 + s1 - v1;
}

__global__ void scan3_k(const int* __restrict__ excl, const int* __restrict__ aux,
                        int* __restrict__ offs, int N, int E) {
    int i = blockIdx.x * 1024 + threadIdx.x;
    if (i < N) {
        offs[i] = excl[i] + aux[blockIdx.x];
    } else if (i == N) {
        offs[N] = E;
    }
}

// Atomic-free single-pass scatter: esrc[offs[d] + rank[e]] = src[e].
// Every esrc byte is written exactly once; line-allocation overhead is bounded by
// |esrc| = 6.4 MB regardless of access order, so no windowed passes needed.
__global__ __launch_bounds__(256) void scatter1_k(const int* __restrict__ src,
                                                  const int* __restrict__ dst,
                                                  const u16* __restrict__ rank,
                                                  const int* __restrict__ offs,
                                                  int* __restrict__ esrc, int E, int N) {
    int e = blockIdx.x * 256 + threadIdx.x;
    if (e < E) {
        int d = dst[e];
        d = d < 0 ? 0 : (d >= N ? N - 1 : d);
        int s = src[e];
        s = s < 0 ? 0 : (s >= N ? N - 1 : s);
        esrc[offs[d] + (int)rank[e]] = s;
    }
}

// ---------------- GEMM + fused alpha dots ----------------
// H = X @ W (bf16 MFMA, fp32 acc); AS/AD = H . a_src/a_dst from fp32 accs.
// F32IN: X fp32 (convert during staging) else bf16.
template <int K, int DO, bool F32IN>
__global__ __launch_bounds__(256, 2) void gemm_k(const void* __restrict__ Xv,
                                                 const u16* __restrict__ Wf,
                                                 void* __restrict__ Hv,
                                                 const float* __restrict__ a_src,
                                                 const float* __restrict__ a_dst,
                                                 float* __restrict__ AS,
                                                 float* __restrict__ AD, int nrow) {
    constexpr int BM = 128, BK = 64;
    __shared__ alignas(16) u16 At[BM * BK];  // 16 KB bf16, XOR-swizzled 16B units
    const int tid = threadIdx.x;
    const int wave = tid >> 6, lane = tid & 63;
    const int quad = lane >> 4, l16 = lane & 15;
    const int row0 = blockIdx.x * BM;

    floatx4 acc[2][DO / 16];
#pragma unroll
    for (int a = 0; a < 2; a++)
#pragma unroll
        for (int b = 0; b < DO / 16; b++) acc[a][b] = floatx4{0.f, 0.f, 0.f, 0.f};

    for (int kt = 0; kt < K / BK; ++kt) {
        __syncthreads();
#pragma unroll
        for (int i = 0; i < 4; ++i) {
            int seg = tid + i * 256;          // 1024 segments of 8 k-elements
            int r = seg >> 3, c = seg & 7;
            int gr = row0 + r;
            gr = gr < nrow ? gr : nrow - 1;   // clamp (pad rows discarded on store)
            if (F32IN) {
                const float* X = (const float*)Xv;
                float4 v0 = *(const float4*)(X + (size_t)gr * K + kt * BK + c * 8);
                float4 v1 = *(const float4*)(X + (size_t)gr * K + kt * BK + c * 8 + 4);
                int4 pk;
                pk.x = (int)cvt_pk_bf16(v0.x, v0.y);
                pk.y = (int)cvt_pk_bf16(v0.z, v0.w);
                pk.z = (int)cvt_pk_bf16(v1.x, v1.y);
                pk.w = (int)cvt_pk_bf16(v1.z, v1.w);
                *(int4*)(At + r * BK + (c ^ (r & 7)) * 8) = pk;
            } else {
                const u16* X = (const u16*)Xv;
                int4 v = *(const int4*)(X + (size_t)gr * K + kt * BK + c * 8);
                *(int4*)(At + r * BK + (c ^ (r & 7)) * 8) = v;
            }
        }
        __syncthreads();
#pragma unroll
        for (int ks = 0; ks < 2; ++ks) {
            short8 bfr[DO / 16];
            int kq = kt * 8 + ks * 4 + quad;
#pragma unroll
            for (int ct = 0; ct < DO / 16; ++ct)
                bfr[ct] = *(const short8*)(Wf + ((size_t)kq * DO + ct * 16 + l16) * 8);
#pragma unroll
            for (int rt = 0; rt < 2; ++rt) {
                int row = wave * 32 + rt * 16 + l16;
                int unit = (ks * 4 + quad) ^ (row & 7);
                short8 afr = *(const short8*)(At + row * BK + unit * 8);
#pragma unroll
                for (int ct = 0; ct < DO / 16; ++ct)
                    acc[rt][ct] =
                        __builtin_amdgcn_mfma_f32_16x16x32_bf16(afr, bfr[ct], acc[rt][ct], 0, 0, 0);
            }
        }
    }
    // Epilogue. C/D layout: col = ct*16 + l16, row = quad*4 + r  [m89/m91 verified].
    float asv[DO / 16], adv[DO / 16];
#pragma unroll
    for (int ct = 0; ct < DO / 16; ++ct) {
        asv[ct] = a_src[ct * 16 + l16];
        adv[ct] = a_dst[ct * 16 + l16];
    }
#pragma unroll
    for (int rt = 0; rt < 2; ++rt)
#pragma unroll
        for (int r = 0; r < 4; ++r) {
            int grow = row0 + wave * 32 + rt * 16 + quad * 4 + r;
            bool ok = grow < nrow;
            float ps = 0.f, pd = 0.f;
#pragma unroll
            for (int ct = 0; ct < DO / 16; ++ct) {
                float v = acc[rt][ct][r];
                ps = fmaf(v, asv[ct], ps);
                pd = fmaf(v, adv[ct], pd);
                if (ok) ((u16*)Hv)[(size_t)grow * DO + ct * 16 + l16] = f2bf(v);
            }
            // reduce over the 16-lane col group (xor bits 0-3 stay within quad)
#pragma unroll
            for (int o = 1; o < 16; o <<= 1) {
                ps += __shfl_xor(ps, o);
                pd += __shfl_xor(pd, o);
            }
            if (ok && l16 == 0) {
                AS[grow] = ps;
                AD[grow] = pd;
            }
        }
}

// ---------------- fused segment softmax + aggregate (one wave per dst node) ----------------
// Gather scheme: 16 lanes own one edge-row; a wave processes 4 edges per load
// instruction. Row = 256B (DO=128 bf16) or 128B (DO=64 bf16).
// HB: h rows bf16 (else fp32). OUTB: write bf16 packed (else fp32).
template <int DO, bool HB, bool OUTB>
__global__ __launch_bounds__(256) void agg_k(const void* __restrict__ Hv,
                                             const float* __restrict__ AS,
                                             const float* __restrict__ AD,
                                             const int* __restrict__ offs,
                                             const int* __restrict__ esrc,
                                             const float* __restrict__ bias,
                                             void* __restrict__ OUT, int N) {
    constexpr int NC = HB ? DO / 16 : 4;  // floats per lane slice (bf16: DO/16, fp32: 4)
    const int wave = threadIdx.x >> 6, lane = threadIdx.x & 63;
    const int sub = lane >> 4, l16 = lane & 15;
    const int d = blockIdx.x * 4 + wave;
    if (d >= N) return;
    const int o0 = offs[d];
    const int deg = offs[d + 1] - o0;  // real in-edges
    const int tot = deg + 1;           // + self loop
    const float ad = AD[d];

    float acc[NC];
#pragma unroll
    for (int c = 0; c < NC; ++c) acc[c] = 0.f;

    // gather one row-slice of row sl with weight wl
    auto gath = [&](float wl, int sl) {
        if (HB) {
            if (DO == 128) {
                uint4 hv = ((const uint4*)Hv)[(size_t)sl * 16 + l16];
                u32 p[4] = {hv.x, hv.y, hv.z, hv.w};
#pragma unroll
                for (int c = 0; c < 4; ++c) {
                    acc[2 * c] = fmaf(wl, bf2f((u16)p[c]), acc[2 * c]);
                    acc[2 * c + 1] = fmaf(wl, bf2f((u16)(p[c] >> 16)), acc[2 * c + 1]);
                }
            } else {
                uint2 hv = ((const uint2*)Hv)[(size_t)sl * 16 + l16];
                acc[0] = fmaf(wl, bf2f((u16)hv.x), acc[0]);
                acc[1] = fmaf(wl, bf2f((u16)(hv.x >> 16)), acc[1]);
                acc[2] = fmaf(wl, bf2f((u16)hv.y), acc[2]);
                acc[3] = fmaf(wl, bf2f((u16)(hv.y >> 16)), acc[3]);
            }
        } else {
            float4 hv = ((const float4*)Hv)[(size_t)sl * 16 + l16];
            acc[0] = fmaf(wl, hv.x, acc[0]);
            acc[1] = fmaf(wl, hv.y, acc[1]);
            acc[2] = fmaf(wl, hv.z, acc[2]);
            acc[3] = fmaf(wl, hv.w, acc[3]);
        }
    };
    // 4 edges starting at l: sub-group `sub` takes edge l+sub (w,s live in lane idx)
    auto quad = [&](float w, int s, int l, int lim) {
        int idx = l + sub;
        int cl = idx < lim ? idx : lim - 1;
        float wv = __shfl(w, cl);  // ds_bpermute, per-lane src index
        int sl = __shfl(s, cl);
        gath(idx < lim ? wv : 0.f, sl);
    };

    if (tot <= 64) {
        // ---- fast path: whole segment resident in one wave, single gather pass ----
        int s = (lane < deg) ? esrc[o0 + lane] : d;  // lane==deg -> self loop
        bool valid = lane < tot;
        float lg = AS[s] + ad;
        lg = lg > 0.f ? lg : lg * 0.2f;
        float lgv = valid ? lg : -1e30f;
        float m = lgv;
        for (int o = 32; o; o >>= 1) m = fmaxf(m, __shfl_xor(m, o));
        float e = valid ? __expf(lg - m) : 0.f;
        float sum = e;
        for (int o = 32; o; o >>= 1) sum += __shfl_xor(sum, o);
        float w = e * (1.f / sum);
        for (int l = 0; l < tot; l += 16) {
#pragma unroll
            for (int g = 0; g < 4; ++g)
                if (l + g * 4 < tot) quad(w, s, l + g * 4, tot);
        }
    } else {
        // ---- general path (deg > 63, rare at avg deg 16): 3-pass ----
        float mx = -1e30f;
        for (int i = lane; i < tot; i += 64) {
            int s = (i < deg) ? esrc[o0 + i] : d;
            float lg = AS[s] + ad;
            lg = lg > 0.f ? lg : lg * 0.2f;
            mx = fmaxf(mx, lg);
        }
        for (int o = 32; o; o >>= 1) mx = fmaxf(mx, __shfl_xor(mx, o));
        float sum = 0.f;
        for (int i = lane; i < tot; i += 64) {
            int s = (i < deg) ? esrc[o0 + i] : d;
            float lg = AS[s] + ad;
            lg = lg > 0.f ? lg : lg * 0.2f;
            sum += __expf(lg - mx);
        }
        for (int o = 32; o; o >>= 1) sum += __shfl_xor(sum, o);
        const float inv = 1.f / sum;
        for (int c0 = 0; c0 < tot; c0 += 64) {
            int i = c0 + lane;
            float w = 0.f;
            int s = d;
            if (i < tot) {
                s = (i < deg) ? esrc[o0 + i] : d;
                float lg = AS[s] + ad;
                lg = lg > 0.f ? lg : lg * 0.2f;
                w = __expf(lg - mx) * inv;
            }
            int cn = tot - c0;
            cn = cn < 64 ? cn : 64;
            for (int l = 0; l < cn; l += 16) {
#pragma unroll
                for (int g = 0; g < 4; ++g)
                    if (l + g * 4 < cn) quad(w, s, l + g * 4, cn);
            }
        }
    }

    // fold the 4 edge-subsets
#pragma unroll
    for (int c = 0; c < NC; ++c) {
        acc[c] += __shfl_xor(acc[c], 16);
        acc[c] += __shfl_xor(acc[c], 32);
    }

    // epilogue: + bias, leaky_relu(0.25), store (sub==0 lanes write their slice)
    if (sub == 0) {
        if (DO == 128) {
            u32 pk[4];
            float fv[8];
#pragma unroll
            for (int c = 0; c < 8; ++c) {
                float v = acc[c] + bias[l16 * 8 + c];
                fv[c] = v > 0.f ? v : v * 0.25f;
            }
            if (OUTB) {
#pragma unroll
                for (int c = 0; c < 4; ++c)
                    pk[c] = (u32)f2bf(fv[2 * c]) | ((u32)f2bf(fv[2 * c + 1]) << 16);
                ((uint4*)OUT)[(size_t)d * 16 + l16] = uint4{pk[0], pk[1], pk[2], pk[3]};
            } else {
                float4 o0v = float4{fv[0], fv[1], fv[2], fv[3]};
                float4 o1v = float4{fv[4], fv[5], fv[6], fv[7]};
                ((float4*)OUT)[(size_t)d * 32 + l16 * 2] = o0v;
                ((float4*)OUT)[(size_t)d * 32 + l16 * 2 + 1] = o1v;
            }
        } else {
            float4 v;
            v.x = acc[0] + bias[l16 * 4 + 0];
            v.y = acc[1] + bias[l16 * 4 + 1];
            v.z = acc[2] + bias[l16 * 4 + 2];
            v.w = acc[3] + bias[l16 * 4 + 3];
            v.x = v.x > 0.f ? v.x : v.x * 0.25f;
            v.y = v.y > 0.f ? v.y : v.y * 0.25f;
            v.z = v.z > 0.f ? v.z : v.z * 0.25f;
            v.w = v.w > 0.f ? v.w : v.w * 0.25f;
            if (OUTB) {
                u32 p0 = (u32)f2bf(v.x) | ((u32)f2bf(v.y) << 16);
                u32 p1 = (u32)f2bf(v.z) | ((u32)f2bf(v.w) << 16);
                ((uint2*)OUT)[(size_t)d * 16 + l16] = uint2{p0, p1};
            } else {
                ((float4*)OUT)[(size_t)d * 16 + l16] = v;
            }
        }
    }
}

// ---------------- launch ----------------

extern "C" void kernel_launch(void* const* d_in, const int* in_sizes, int n_in,
                              void* d_out, int out_size, void* d_ws, size_t ws_size,
                              hipStream_t stream) {
    const int N = in_sizes[0] / 512;  // 100000
    const int E = in_sizes[1] / 2;    // 1600000

    const float* data = (const float*)d_in[0];
    const int* adj = (const int*)d_in[1];
    const float* W1 = (const float*)d_in[2];
    const float* as1 = (const float*)d_in[3];
    const float* ad1 = (const float*)d_in[4];
    const float* b1 = (const float*)d_in[5];
    const float* W2 = (const float*)d_in[6];
    const float* as2 = (const float*)d_in[7];
    const float* ad2 = (const float*)d_in[8];
    const float* b2 = (const float*)d_in[9];
    const float* W3 = (const float*)d_in[10];
    const float* as3 = (const float*)d_in[11];
    const float* ad3 = (const float*)d_in[12];
    const float* b3 = (const float*)d_in[13];

    // ---- workspace carve + budget check ----
    char* ws = (char*)d_ws;
    size_t need = 0;
    auto carve = [&](size_t bytes) {
        void* p = (void*)(ws + need);
        need += (bytes + 255) & ~(size_t)255;
        return p;
    };
    int* esrc = (int*)carve((size_t)E * 4);
    int* offs = (int*)carve((size_t)(N + 1) * 4);
    int* cnt = (int*)carve((size_t)N * 4);
    int* excl = (int*)carve((size_t)N * 4);
    int* aux = (int*)carve(1024);
    float* AS = (float*)carve((size_t)N * 4);
    float* AD = (float*)carve((size_t)N * 4);
    u16* rank = (u16*)carve((size_t)E * 2);
    u16* Hb = (u16*)carve((size_t)N * 128 * 2);  // bf16 h (all 3 layers; L3 uses 64 cols)
    u16* x1 = (u16*)carve((size_t)N * 128 * 2);  // bf16 next-layer input
    u16* x2 = x1;                                // x1 dead after layer-2 GEMM
    u16* Wf1 = (u16*)carve(512 * 128 * 2);
    u16* Wf2 = (u16*)carve(128 * 128 * 2);
    u16* Wf3 = (u16*)carve(128 * 64 * 2);

    if (need > ws_size) {
        // Diagnostic signature: absmax == ref absmax (0.2373) => ws too small.
        zero_out_k<<<(out_size + 255) / 256, 256, 0, stream>>>((float*)d_out, out_size);
        return;
    }

    const int* srcl = adj;
    const int* dstl = adj + E;

    const int gblk = (N + 127) / 128;
    const int nblk = (N + 3) / 4;
    const int nhist = (E + 255) / 256;

    // ---- CSR build (standalone, high-occupancy) + all weight prepack ----
    hipMemsetAsync(cnt, 0, (size_t)N * 4, stream);
    hist_prepack_k<<<nhist, 256, 0, stream>>>(dstl, cnt, rank, E, N,
                                              W1, Wf1, W2, Wf2, W3, Wf3);
    int nb = (N + 1023) / 1024;
    scan1_k<<<nb, 1024, 0, stream>>>(cnt, excl, aux, N);
    scan2_k<<<1, 64, 0, stream>>>(aux, nb);
    scan3_k<<<nb, 1024, 0, stream>>>(excl, aux, offs, N, E);
    scatter1_k<<<nhist, 256, 0, stream>>>(srcl, dstl, rank, offs, esrc, E, N);

    // ---- layer 1 ----
    gemm_k<512, 128, true><<<gblk, 256, 0, stream>>>(data, Wf1, Hb, as1, ad1, AS, AD, N);
    agg_k<128, true, true><<<nblk, 256, 0, stream>>>(Hb, AS, AD, offs, esrc, b1, x1, N);
    // ---- layer 2 ----
    gemm_k<128, 128, false><<<gblk, 256, 0, stream>>>(x1, Wf2, Hb, as2, ad2, AS, AD, N);
    agg_k<128, true, true><<<nblk, 256, 0, stream>>>(Hb, AS, AD, offs, esrc, b2, x2, N);
    // ---- layer 3: h3 bf16 (128B rows) ----
    gemm_k<128, 64, false><<<gblk, 256, 0, stream>>>(x2, Wf3, Hb, as3, ad3, AS, AD, N);
    agg_k<64, true, false><<<nblk, 256, 0, stream>>>(Hb, AS, AD, offs, esrc, b3, d_out, N);
}

// Round 6
// 676.168 us; speedup vs baseline: 1.0059x; 1.0059x over previous
//
#include <hip/hip_runtime.h>

typedef unsigned short u16;
typedef unsigned int u32;
typedef short short8 __attribute__((ext_vector_type(8)));
typedef float floatx4 __attribute__((ext_vector_type(4)));

__device__ __forceinline__ float bf2f(u16 x) { return __uint_as_float(((u32)x) << 16); }
__device__ __forceinline__ u16 f2bf(float x) {
    u32 u = __float_as_uint(x);
    u += 0x7fffu + ((u >> 16) & 1u);
    return (u16)(u >> 16);
}
// pack two fp32 -> u32 of 2 bf16 (RNE), single HW instruction
__device__ __forceinline__ u32 cvt_pk_bf16(float lo, float hi) {
    u32 r;
    asm("v_cvt_pk_bf16_f32 %0, %1, %2" : "=v"(r) : "v"(lo), "v"(hi));
    return r;
}

// ---------------- diagnostic: zero the output (fp32) ----------------
__global__ void zero_out_k(float* __restrict__ out, int n) {
    int i = blockIdx.x * 256 + threadIdx.x;
    if (i < n) out[i] = 0.f;
}

// ---------------- weight prepack helper ----------------
// Wf[(kq*DO + n)*8 + j] = bf16(W[(kq*8 + j)*DO + n])   (k = kq*8 + j)
__device__ __forceinline__ void prepack1(const float* W, u16* Wf, int DO, int idx) {
    int j = idx & 7;
    int t = idx >> 3;
    int n = t % DO;
    int kq = t / DO;
    Wf[idx] = f2bf(W[(size_t)(kq * 8 + j) * DO + n]);
}

// ---------------- CSR histogram+rank, ILP-8 (+all-3 weight prepack piggyback) ----
// hist is latency-bound random atomics (R4/R5 isolation: ~110 us at 1 atomic/thread).
// Each thread owns 8 consecutive edges: 2x int4 dst load, 8 INDEPENDENT returning
// atomics in flight (one vmcnt wait), one 16B coalesced rank store.
__global__ void hist_prepack_k(const int* __restrict__ dst, int* __restrict__ cnt,
                               u16* __restrict__ rank, int E, int N,
                               const float* __restrict__ W1, u16* __restrict__ Wf1,
                               const float* __restrict__ W2, u16* __restrict__ Wf2,
                               const float* __restrict__ W3, u16* __restrict__ Wf3) {
    int t = blockIdx.x * 256 + threadIdx.x;
    int e8 = t * 8;
    if (e8 + 7 < E) {
        int4 d0 = *(const int4*)(dst + e8);
        int4 d1 = *(const int4*)(dst + e8 + 4);
        int dd[8] = {d0.x, d0.y, d0.z, d0.w, d1.x, d1.y, d1.z, d1.w};
        u16 rk[8];
#pragma unroll
        for (int j = 0; j < 8; ++j) {
            int d = dd[j];
            d = d < 0 ? 0 : (d >= N ? N - 1 : d);
            rk[j] = (u16)atomicAdd(&cnt[d], 1);  // 8 independent, pipelined
        }
        *(uint4*)(rank + e8) = *(const uint4*)rk;
    } else {
        for (int j = 0; j < 8; ++j) {
            int e = e8 + j;
            if (e < E) {
                int d = dst[e];
                d = d < 0 ? 0 : (d >= N ? N - 1 : d);
                rank[e] = (u16)atomicAdd(&cnt[d], 1);
            }
        }
    }
    const int T1 = 512 * 128, T2 = 128 * 128, T3 = 128 * 64;
    if (t < T1) prepack1(W1, Wf1, 128, t);
    else if (t < T1 + T2) prepack1(W2, Wf2, 128, t - T1);
    else if (t < T1 + T2 + T3) prepack1(W3, Wf3, 64, t - T1 - T2);
}

// ---------------- scans ----------------
// block-level exclusive scan: 16 waves, shfl-scan per wave + cross-wave LDS combine
__global__ void scan1_k(const int* __restrict__ cnt, int* __restrict__ excl,
                        int* __restrict__ aux, int N) {
    __shared__ int wsum[16];
    int t = threadIdx.x;
    int wv = t >> 6, ln = t & 63;
    int i = blockIdx.x * 1024 + t;
    int v = (i < N) ? cnt[i] : 0;
    int s = v;
    for (int off = 1; off < 64; off <<= 1) { int x = __shfl_up(s, off); if (ln >= off) s += x; }
    if (ln == 63) wsum[wv] = s;
    __syncthreads();
    if (wv == 0) {
        int ws = (ln < 16) ? wsum[ln] : 0;
        int ss = ws;
        for (int off = 1; off < 16; off <<= 1) { int x = __shfl_up(ss, off); if (ln >= off) ss += x; }
        if (ln < 16) wsum[ln] = ss - ws;  // exclusive wave offsets
    }
    __syncthreads();
    int base = wsum[wv];
    if (i < N) excl[i] = base + s - v;
    if (t == 1023) aux[blockIdx.x] = base + s;
}

__global__ void scan2_k(int* __restrict__ aux, int nb) {
    int lane = threadIdx.x;  // single block of 64; nb <= 128
    int v0 = (lane < nb) ? aux[lane] : 0;
    int v1 = (lane + 64 < nb) ? aux[lane + 64] : 0;
    int s0 = v0;
    for (int off = 1; off < 64; off <<= 1) { int x = __shfl_up(s0, off); if (lane >= off) s0 += x; }
    int total0 = __shfl(s0, 63);
    int s1 = v1;
    for (int off = 1; off < 64; off <<= 1) { int x = __shfl_up(s1, off); if (lane >= off) s1 += x; }
    if (lane < nb) aux[lane] = s0 - v0;
    if (lane + 64 < nb) aux[lane + 64] = total0 + s1 - v1;
}

__global__ void scan3_k(const int* __restrict__ excl, const int* __restrict__ aux,
                        int* __restrict__ offs, int N, int E) {
    int i = blockIdx.x * 1024 + threadIdx.x;
    if (i < N) {
        offs[i] = excl[i] + aux[blockIdx.x];
    } else if (i == N) {
        offs[N] = E;
    }
}

// Atomic-free scatter: esrc[offs[d] + rank[e]] = src[e].
// NPASS dst-range passes confine the random-write window (~800 KB < per-XCD L2)
// so partial lines merge before HBM writeback (R3 vs R5: 8-pass beats 1-pass).
template <int NPASS>
__global__ __launch_bounds__(256) void scatter_nr_k(const int* __restrict__ src,
                                                    const int* __restrict__ dst,
                                                    const u16* __restrict__ rank,
                                                    const int* __restrict__ offs,
                                                    int* __restrict__ esrc, int E, int N) {
    const int stride = gridDim.x * 256;
    const int t0 = blockIdx.x * 256 + threadIdx.x;
    const int span = (N + NPASS - 1) / NPASS;
#pragma unroll 1
    for (int p = 0; p < NPASS; ++p) {
        const int lo = p * span, hi = lo + span;
        for (int e = t0; e < E; e += stride) {
            int d = dst[e];
            d = d < 0 ? 0 : (d >= N ? N - 1 : d);
            if (d >= lo && d < hi) {
                int s = src[e];
                s = s < 0 ? 0 : (s >= N ? N - 1 : s);
                esrc[offs[d] + (int)rank[e]] = s;
            }
        }
    }
}

// ---------------- GEMM + fused alpha dots ----------------
// H = X @ W (bf16 MFMA, fp32 acc); AS/AD = H . a_src/a_dst from fp32 accs.
// F32IN: X fp32 (convert during staging) else bf16.
template <int K, int DO, bool F32IN>
__global__ __launch_bounds__(256, 2) void gemm_k(const void* __restrict__ Xv,
                                                 const u16* __restrict__ Wf,
                                                 void* __restrict__ Hv,
                                                 const float* __restrict__ a_src,
                                                 const float* __restrict__ a_dst,
                                                 float* __restrict__ AS,
                                                 float* __restrict__ AD, int nrow) {
    constexpr int BM = 128, BK = 64;
    __shared__ alignas(16) u16 At[BM * BK];  // 16 KB bf16, XOR-swizzled 16B units
    const int tid = threadIdx.x;
    const int wave = tid >> 6, lane = tid & 63;
    const int quad = lane >> 4, l16 = lane & 15;
    const int row0 = blockIdx.x * BM;

    floatx4 acc[2][DO / 16];
#pragma unroll
    for (int a = 0; a < 2; a++)
#pragma unroll
        for (int b = 0; b < DO / 16; b++) acc[a][b] = floatx4{0.f, 0.f, 0.f, 0.f};

    for (int kt = 0; kt < K / BK; ++kt) {
        __syncthreads();
#pragma unroll
        for (int i = 0; i < 4; ++i) {
            int seg = tid + i * 256;          // 1024 segments of 8 k-elements
            int r = seg >> 3, c = seg & 7;
            int gr = row0 + r;
            gr = gr < nrow ? gr : nrow - 1;   // clamp (pad rows discarded on store)
            if (F32IN) {
                const float* X = (const float*)Xv;
                float4 v0 = *(const float4*)(X + (size_t)gr * K + kt * BK + c * 8);
                float4 v1 = *(const float4*)(X + (size_t)gr * K + kt * BK + c * 8 + 4);
                int4 pk;
                pk.x = (int)cvt_pk_bf16(v0.x, v0.y);
                pk.y = (int)cvt_pk_bf16(v0.z, v0.w);
                pk.z = (int)cvt_pk_bf16(v1.x, v1.y);
                pk.w = (int)cvt_pk_bf16(v1.z, v1.w);
                *(int4*)(At + r * BK + (c ^ (r & 7)) * 8) = pk;
            } else {
                const u16* X = (const u16*)Xv;
                int4 v = *(const int4*)(X + (size_t)gr * K + kt * BK + c * 8);
                *(int4*)(At + r * BK + (c ^ (r & 7)) * 8) = v;
            }
        }
        __syncthreads();
#pragma unroll
        for (int ks = 0; ks < 2; ++ks) {
            short8 bfr[DO / 16];
            int kq = kt * 8 + ks * 4 + quad;
#pragma unroll
            for (int ct = 0; ct < DO / 16; ++ct)
                bfr[ct] = *(const short8*)(Wf + ((size_t)kq * DO + ct * 16 + l16) * 8);
#pragma unroll
            for (int rt = 0; rt < 2; ++rt) {
                int row = wave * 32 + rt * 16 + l16;
                int unit = (ks * 4 + quad) ^ (row & 7);
                short8 afr = *(const short8*)(At + row * BK + unit * 8);
#pragma unroll
                for (int ct = 0; ct < DO / 16; ++ct)
                    acc[rt][ct] =
                        __builtin_amdgcn_mfma_f32_16x16x32_bf16(afr, bfr[ct], acc[rt][ct], 0, 0, 0);
            }
        }
    }
    // Epilogue. C/D layout: col = ct*16 + l16, row = quad*4 + r  [m89/m91 verified].
    float asv[DO / 16], adv[DO / 16];
#pragma unroll
    for (int ct = 0; ct < DO / 16; ++ct) {
        asv[ct] = a_src[ct * 16 + l16];
        adv[ct] = a_dst[ct * 16 + l16];
    }
#pragma unroll
    for (int rt = 0; rt < 2; ++rt)
#pragma unroll
        for (int r = 0; r < 4; ++r) {
            int grow = row0 + wave * 32 + rt * 16 + quad * 4 + r;
            bool ok = grow < nrow;
            float ps = 0.f, pd = 0.f;
#pragma unroll
            for (int ct = 0; ct < DO / 16; ++ct) {
                float v = acc[rt][ct][r];
                ps = fmaf(v, asv[ct], ps);
                pd = fmaf(v, adv[ct], pd);
                if (ok) ((u16*)Hv)[(size_t)grow * DO + ct * 16 + l16] = f2bf(v);
            }
            // reduce over the 16-lane col group (xor bits 0-3 stay within quad)
#pragma unroll
            for (int o = 1; o < 16; o <<= 1) {
                ps += __shfl_xor(ps, o);
                pd += __shfl_xor(pd, o);
            }
            if (ok && l16 == 0) {
                AS[grow] = ps;
                AD[grow] = pd;
            }
        }
}

// ---------------- fused segment softmax + aggregate (one wave per dst node) ----------------
// Gather scheme: 16 lanes own one edge-row; a wave processes 4 edges per load
// instruction. Row = 256B (DO=128 bf16) or 128B (DO=64 bf16).
// HB: h rows bf16 (else fp32). OUTB: write bf16 packed (else fp32).
template <int DO, bool HB, bool OUTB>
__global__ __launch_bounds__(256) void agg_k(const void* __restrict__ Hv,
                                             const float* __restrict__ AS,
                                             const float* __restrict__ AD,
                                             const int* __restrict__ offs,
                                             const int* __restrict__ esrc,
                                             const float* __restrict__ bias,
                                             void* __restrict__ OUT, int N) {
    constexpr int NC = HB ? DO / 16 : 4;  // floats per lane slice (bf16: DO/16, fp32: 4)
    const int wave = threadIdx.x >> 6, lane = threadIdx.x & 63;
    const int sub = lane >> 4, l16 = lane & 15;
    const int d = blockIdx.x * 4 + wave;
    if (d >= N) return;
    const int o0 = offs[d];
    const int deg = offs[d + 1] - o0;  // real in-edges
    const int tot = deg + 1;           // + self loop
    const float ad = AD[d];

    float acc[NC];
#pragma unroll
    for (int c = 0; c < NC; ++c) acc[c] = 0.f;

    // gather one row-slice of row sl with weight wl
    auto gath = [&](float wl, int sl) {
        if (HB) {
            if (DO == 128) {
                uint4 hv = ((const uint4*)Hv)[(size_t)sl * 16 + l16];
                u32 p[4] = {hv.x, hv.y, hv.z, hv.w};
#pragma unroll
                for (int c = 0; c < 4; ++c) {
                    acc[2 * c] = fmaf(wl, bf2f((u16)p[c]), acc[2 * c]);
                    acc[2 * c + 1] = fmaf(wl, bf2f((u16)(p[c] >> 16)), acc[2 * c + 1]);
                }
            } else {
                uint2 hv = ((const uint2*)Hv)[(size_t)sl * 16 + l16];
                acc[0] = fmaf(wl, bf2f((u16)hv.x), acc[0]);
                acc[1] = fmaf(wl, bf2f((u16)(hv.x >> 16)), acc[1]);
                acc[2] = fmaf(wl, bf2f((u16)hv.y), acc[2]);
                acc[3] = fmaf(wl, bf2f((u16)(hv.y >> 16)), acc[3]);
            }
        } else {
            float4 hv = ((const float4*)Hv)[(size_t)sl * 16 + l16];
            acc[0] = fmaf(wl, hv.x, acc[0]);
            acc[1] = fmaf(wl, hv.y, acc[1]);
            acc[2] = fmaf(wl, hv.z, acc[2]);
            acc[3] = fmaf(wl, hv.w, acc[3]);
        }
    };
    // 4 edges starting at l: sub-group `sub` takes edge l+sub (w,s live in lane idx)
    auto quad = [&](float w, int s, int l, int lim) {
        int idx = l + sub;
        int cl = idx < lim ? idx : lim - 1;
        float wv = __shfl(w, cl);  // ds_bpermute, per-lane src index
        int sl = __shfl(s, cl);
        gath(idx < lim ? wv : 0.f, sl);
    };

    if (tot <= 64) {
        // ---- fast path: whole segment resident in one wave, single gather pass ----
        int s = (lane < deg) ? esrc[o0 + lane] : d;  // lane==deg -> self loop
        bool valid = lane < tot;
        float lg = AS[s] + ad;
        lg = lg > 0.f ? lg : lg * 0.2f;
        float lgv = valid ? lg : -1e30f;
        float m = lgv;
        for (int o = 32; o; o >>= 1) m = fmaxf(m, __shfl_xor(m, o));
        float e = valid ? __expf(lg - m) : 0.f;
        float sum = e;
        for (int o = 32; o; o >>= 1) sum += __shfl_xor(sum, o);
        float w = e * (1.f / sum);
        for (int l = 0; l < tot; l += 16) {
#pragma unroll
            for (int g = 0; g < 4; ++g)
                if (l + g * 4 < tot) quad(w, s, l + g * 4, tot);
        }
    } else {
        // ---- general path (deg > 63, rare at avg deg 16): 3-pass ----
        float mx = -1e30f;
        for (int i = lane; i < tot; i += 64) {
            int s = (i < deg) ? esrc[o0 + i] : d;
            float lg = AS[s] + ad;
            lg = lg > 0.f ? lg : lg * 0.2f;
            mx = fmaxf(mx, lg);
        }
        for (int o = 32; o; o >>= 1) mx = fmaxf(mx, __shfl_xor(mx, o));
        float sum = 0.f;
        for (int i = lane; i < tot; i += 64) {
            int s = (i < deg) ? esrc[o0 + i] : d;
            float lg = AS[s] + ad;
            lg = lg > 0.f ? lg : lg * 0.2f;
            sum += __expf(lg - mx);
        }
        for (int o = 32; o; o >>= 1) sum += __shfl_xor(sum, o);
        const float inv = 1.f / sum;
        for (int c0 = 0; c0 < tot; c0 += 64) {
            int i = c0 + lane;
            float w = 0.f;
            int s = d;
            if (i < tot) {
                s = (i < deg) ? esrc[o0 + i] : d;
                float lg = AS[s] + ad;
                lg = lg > 0.f ? lg : lg * 0.2f;
                w = __expf(lg - mx) * inv;
            }
            int cn = tot - c0;
            cn = cn < 64 ? cn : 64;
            for (int l = 0; l < cn; l += 16) {
#pragma unroll
                for (int g = 0; g < 4; ++g)
                    if (l + g * 4 < cn) quad(w, s, l + g * 4, cn);
            }
        }
    }

    // fold the 4 edge-subsets
#pragma unroll
    for (int c = 0; c < NC; ++c) {
        acc[c] += __shfl_xor(acc[c], 16);
        acc[c] += __shfl_xor(acc[c], 32);
    }

    // epilogue: + bias, leaky_relu(0.25), store (sub==0 lanes write their slice)
    if (sub == 0) {
        if (DO == 128) {
            u32 pk[4];
            float fv[8];
#pragma unroll
            for (int c = 0; c < 8; ++c) {
                float v = acc[c] + bias[l16 * 8 + c];
                fv[c] = v > 0.f ? v : v * 0.25f;
            }
            if (OUTB) {
#pragma unroll
                for (int c = 0; c < 4; ++c)
                    pk[c] = (u32)f2bf(fv[2 * c]) | ((u32)f2bf(fv[2 * c + 1]) << 16);
                ((uint4*)OUT)[(size_t)d * 16 + l16] = uint4{pk[0], pk[1], pk[2], pk[3]};
            } else {
                float4 o0v = float4{fv[0], fv[1], fv[2], fv[3]};
                float4 o1v = float4{fv[4], fv[5], fv[6], fv[7]};
                ((float4*)OUT)[(size_t)d * 32 + l16 * 2] = o0v;
                ((float4*)OUT)[(size_t)d * 32 + l16 * 2 + 1] = o1v;
            }
        } else {
            float4 v;
            v.x = acc[0] + bias[l16 * 4 + 0];
            v.y = acc[1] + bias[l16 * 4 + 1];
            v.z = acc[2] + bias[l16 * 4 + 2];
            v.w = acc[3] + bias[l16 * 4 + 3];
            v.x = v.x > 0.f ? v.x : v.x * 0.25f;
            v.y = v.y > 0.f ? v.y : v.y * 0.25f;
            v.z = v.z > 0.f ? v.z : v.z * 0.25f;
            v.w = v.w > 0.f ? v.w : v.w * 0.25f;
            if (OUTB) {
                u32 p0 = (u32)f2bf(v.x) | ((u32)f2bf(v.y) << 16);
                u32 p1 = (u32)f2bf(v.z) | ((u32)f2bf(v.w) << 16);
                ((uint2*)OUT)[(size_t)d * 16 + l16] = uint2{p0, p1};
            } else {
                ((float4*)OUT)[(size_t)d * 16 + l16] = v;
            }
        }
    }
}

// ---------------- launch ----------------

extern "C" void kernel_launch(void* const* d_in, const int* in_sizes, int n_in,
                              void* d_out, int out_size, void* d_ws, size_t ws_size,
                              hipStream_t stream) {
    const int N = in_sizes[0] / 512;  // 100000
    const int E = in_sizes[1] / 2;    // 1600000

    const float* data = (const float*)d_in[0];
    const int* adj = (const int*)d_in[1];
    const float* W1 = (const float*)d_in[2];
    const float* as1 = (const float*)d_in[3];
    const float* ad1 = (const float*)d_in[4];
    const float* b1 = (const float*)d_in[5];
    const float* W2 = (const float*)d_in[6];
    const float* as2 = (const float*)d_in[7];
    const float* ad2 = (const float*)d_in[8];
    const float* b2 = (const float*)d_in[9];
    const float* W3 = (const float*)d_in[10];
    const float* as3 = (const float*)d_in[11];
    const float* ad3 = (const float*)d_in[12];
    const float* b3 = (const float*)d_in[13];

    // ---- workspace carve + budget check ----
    char* ws = (char*)d_ws;
    size_t need = 0;
    auto carve = [&](size_t bytes) {
        void* p = (void*)(ws + need);
        need += (bytes + 255) & ~(size_t)255;
        return p;
    };
    int* esrc = (int*)carve((size_t)E * 4);
    int* offs = (int*)carve((size_t)(N + 1) * 4);
    int* cnt = (int*)carve((size_t)N * 4);
    int* excl = (int*)carve((size_t)N * 4);
    int* aux = (int*)carve(1024);
    float* AS = (float*)carve((size_t)N * 4);
    float* AD = (float*)carve((size_t)N * 4);
    u16* rank = (u16*)carve((size_t)E * 2);
    u16* Hb = (u16*)carve((size_t)N * 128 * 2);  // bf16 h (all 3 layers; L3 uses 64 cols)
    u16* x1 = (u16*)carve((size_t)N * 128 * 2);  // bf16 next-layer input
    u16* x2 = x1;                                // x1 dead after layer-2 GEMM
    u16* Wf1 = (u16*)carve(512 * 128 * 2);
    u16* Wf2 = (u16*)carve(128 * 128 * 2);
    u16* Wf3 = (u16*)carve(128 * 64 * 2);

    if (need > ws_size) {
        // Diagnostic signature: absmax == ref absmax (0.2373) => ws too small.
        zero_out_k<<<(out_size + 255) / 256, 256, 0, stream>>>((float*)d_out, out_size);
        return;
    }

    const int* srcl = adj;
    const int* dstl = adj + E;

    const int gblk = (N + 127) / 128;
    const int nblk = (N + 3) / 4;

    // ---- CSR build (ILP-8 hist, high-occupancy) + all weight prepack ----
    hipMemsetAsync(cnt, 0, (size_t)N * 4, stream);
    const int nh8 = ((E + 7) / 8 + 255) / 256;
    hist_prepack_k<<<nh8, 256, 0, stream>>>(dstl, cnt, rank, E, N,
                                            W1, Wf1, W2, Wf2, W3, Wf3);
    int nb = (N + 1023) / 1024;
    scan1_k<<<nb, 1024, 0, stream>>>(cnt, excl, aux, N);
    scan2_k<<<1, 64, 0, stream>>>(aux, nb);
    scan3_k<<<nb, 1024, 0, stream>>>(excl, aux, offs, N, E);
    scatter_nr_k<8><<<2048, 256, 0, stream>>>(srcl, dstl, rank, offs, esrc, E, N);

    // ---- layer 1 ----
    gemm_k<512, 128, true><<<gblk, 256, 0, stream>>>(data, Wf1, Hb, as1, ad1, AS, AD, N);
    agg_k<128, true, true><<<nblk, 256, 0, stream>>>(Hb, AS, AD, offs, esrc, b1, x1, N);
    // ---- layer 2 ----
    gemm_k<128, 128, false><<<gblk, 256, 0, stream>>>(x1, Wf2, Hb, as2, ad2, AS, AD, N);
    agg_k<128, true, true><<<nblk, 256, 0, stream>>>(Hb, AS, AD, offs, esrc, b2, x2, N);
    // ---- layer 3: h3 bf16 (128B rows) ----
    gemm_k<128, 64, false><<<gblk, 256, 0, stream>>>(x2, Wf3, Hb, as3, ad3, AS, AD, N);
    agg_k<64, true, false><<<nblk, 256, 0, stream>>>(Hb, AS, AD, offs, esrc, b3, d_out, N);
}

// Round 8
// 640.224 us; speedup vs baseline: 1.0623x; 1.0561x over previous
//
#include <hip/hip_runtime.h>

typedef unsigned short u16;
typedef unsigned int u32;
typedef unsigned long long u64;
typedef short short8 __attribute__((ext_vector_type(8)));
typedef float floatx4 __attribute__((ext_vector_type(4)));

#define B1 256  // blocks in bucket passes A/B

__device__ __forceinline__ float bf2f(u16 x) { return __uint_as_float(((u32)x) << 16); }
__device__ __forceinline__ u16 f2bf(float x) {
    u32 u = __float_as_uint(x);
    u += 0x7fffu + ((u >> 16) & 1u);
    return (u16)(u >> 16);
}
// pack two fp32 -> u32 of 2 bf16 (RNE), single HW instruction
__device__ __forceinline__ u32 cvt_pk_bf16(float lo, float hi) {
    u32 r;
    asm("v_cvt_pk_bf16_f32 %0, %1, %2" : "=v"(r) : "v"(lo), "v"(hi));
    return r;
}

// ---------------- diagnostic: zero the output (fp32) ----------------
__global__ void zero_out_k(float* __restrict__ out, int n) {
    int i = blockIdx.x * 256 + threadIdx.x;
    if (i < n) out[i] = 0.f;
}

// ---------------- weight prepack (fp32 -> bf16 MFMA-fragment order), all 3 ----------------
// Wf[(kq*DO + n)*8 + j] = bf16(W[(kq*8 + j)*DO + n])   (k = kq*8 + j)
__device__ __forceinline__ void prepack1(const float* W, u16* Wf, int DO, int idx) {
    int j = idx & 7;
    int t = idx >> 3;
    int n = t % DO;
    int kq = t / DO;
    Wf[idx] = f2bf(W[(size_t)(kq * 8 + j) * DO + n]);
}

__global__ void prepack3_k(const float* __restrict__ W1, u16* __restrict__ Wf1,
                           const float* __restrict__ W2, u16* __restrict__ Wf2,
                           const float* __restrict__ W3, u16* __restrict__ Wf3) {
    int idx = blockIdx.x * 256 + threadIdx.x;
    const int T1 = 512 * 128, T2 = 128 * 128, T3 = 128 * 64;
    if (idx < T1) prepack1(W1, Wf1, 128, idx);
    else if (idx < T1 + T2) prepack1(W2, Wf2, 128, idx - T1);
    else if (idx < T1 + T2 + T3) prepack1(W3, Wf3, 64, idx - T1 - T2);
}

// ---------------- CSR build: 3-pass bucket sort, ZERO global atomics ----------------
// (R6 post-mortem: E global atomics are throughput-bound at ~14.5 G/s = immovable
//  110 us. Buckets of 128 dst; per-(bucket,block) private runs via a scanned
//  782x256 count matrix; all counting via LDS atomics.)

// pass A: per-block LDS bucket histogram -> M[b*B1 + blk]
__global__ __launch_bounds__(256) void bucketA_k(const int* __restrict__ dst,
                                                 int* __restrict__ M, int E, int N,
                                                 int NBUCK, int TILE) {
    __shared__ u32 h[1024];
    const int blk = blockIdx.x, tid = threadIdx.x;
    for (int i = tid; i < NBUCK; i += 256) h[i] = 0;
    __syncthreads();
    const int e0 = blk * TILE;
    const int e1 = (e0 + TILE < E) ? e0 + TILE : E;
    for (int e = e0 + tid; e < e1; e += 256) {
        int d = dst[e];
        d = d < 0 ? 0 : (d >= N ? N - 1 : d);
        atomicAdd(&h[d >> 7], 1u);
    }
    __syncthreads();
    for (int i = tid; i < NBUCK; i += 256) M[i * B1 + blk] = (int)h[i];
}

// pass B: scatter (dst,src) u64 into bucket regions; per-(bucket,block) runs are
// contiguous (base from scanned matrix + LDS cursor)
__global__ __launch_bounds__(256) void bucketB_k(const int* __restrict__ src,
                                                 const int* __restrict__ dst,
                                                 const int* __restrict__ Ms,
                                                 u64* __restrict__ ebuf, int E, int N,
                                                 int NBUCK, int TILE) {
    __shared__ u32 cur[1024];
    const int blk = blockIdx.x, tid = threadIdx.x;
    for (int i = tid; i < NBUCK; i += 256) cur[i] = (u32)Ms[i * B1 + blk];
    __syncthreads();
    const int e0 = blk * TILE;
    const int e1 = (e0 + TILE < E) ? e0 + TILE : E;
    for (int e = e0 + tid; e < e1; e += 256) {
        int d = dst[e];
        d = d < 0 ? 0 : (d >= N ? N - 1 : d);
        int s = src[e];
        s = s < 0 ? 0 : (s >= N ? N - 1 : s);
        u32 pos = atomicAdd(&cur[d >> 7], 1u);
        ebuf[pos] = ((u64)(u32)d << 32) | (u32)s;
    }
}

// pass C: one block per bucket: local node histogram + scan -> offs, then final esrc
__global__ __launch_bounds__(256) void bucketC_k(const u64* __restrict__ ebuf,
                                                 const int* __restrict__ Ms,
                                                 int* __restrict__ offs,
                                                 int* __restrict__ esrc, int E, int N,
                                                 int NBUCK) {
    const int b = blockIdx.x, tid = threadIdx.x;
    const int d0 = b << 7;
    __shared__ u32 lcnt[128];
    __shared__ u32 loff[128];
    __shared__ u32 wtot;
    if (tid < 128) lcnt[tid] = 0;
    __syncthreads();
    const int bo0 = Ms[b * B1];
    const int bo1 = Ms[(b + 1) * B1];  // Ms[NBUCK*B1] == E (scan3 tail write)
    for (int e = bo0 + tid; e < bo1; e += 256) {
        int d = (int)(ebuf[e] >> 32);
        atomicAdd(&lcnt[d - d0], 1u);
    }
    __syncthreads();
    // exclusive scan of 128 counters (waves 0-1 meaningful; 2-3 compute garbage harmlessly)
    const int ln = tid & 63;
    u32 v = (tid < 128) ? lcnt[tid] : 0;
    u32 s = v;
    for (int off = 1; off < 64; off <<= 1) { u32 x = __shfl_up(s, off); if (ln >= off) s += x; }
    if (tid == 63) wtot = s;
    __syncthreads();
    u32 base = (tid >= 64 && tid < 128) ? wtot : 0;
    if (tid < 128) loff[tid] = base + s - v;
    if (tid == 255 && b == 0) offs[N] = E;
    __syncthreads();
    if (tid < 128) {
        int d = d0 + tid;
        if (d < N) offs[d] = bo0 + (int)loff[tid];
        lcnt[tid] = 0;  // reuse as cursor
    }
    __syncthreads();
    for (int e = bo0 + tid; e < bo1; e += 256) {
        u64 v64 = ebuf[e];
        int d = (int)(v64 >> 32);
        int sc = (int)(v64 & 0xffffffffu);
        u32 slot = atomicAdd(&lcnt[d - d0], 1u);
        esrc[bo0 + (int)loff[d - d0] + slot] = sc;
    }
}

// ---------------- scans ----------------
// block-level exclusive scan: 16 waves, shfl-scan per wave + cross-wave LDS combine
__global__ void scan1_k(const int* __restrict__ cnt, int* __restrict__ excl,
                        int* __restrict__ aux, int N) {
    __shared__ int wsum[16];
    int t = threadIdx.x;
    int wv = t >> 6, ln = t & 63;
    int i = blockIdx.x * 1024 + t;
    int v = (i < N) ? cnt[i] : 0;
    int s = v;
    for (int off = 1; off < 64; off <<= 1) { int x = __shfl_up(s, off); if (ln >= off) s += x; }
    if (ln == 63) wsum[wv] = s;
    __syncthreads();
    if (wv == 0) {
        int ws = (ln < 16) ? wsum[ln] : 0;
        int ss = ws;
        for (int off = 1; off < 16; off <<= 1) { int x = __shfl_up(ss, off); if (ln >= off) ss += x; }
        if (ln < 16) wsum[ln] = ss - ws;  // exclusive wave offsets
    }
    __syncthreads();
    int base = wsum[wv];
    if (i < N) excl[i] = base + s - v;
    if (t == 1023) aux[blockIdx.x] = base + s;
}

// exclusive scan of up to 256 partials, single wave, 4 chunks
__global__ void scan2_k(int* __restrict__ aux, int nb) {
    int lane = threadIdx.x;
    int run = 0;
    for (int c = 0; c < 4; ++c) {
        int i = c * 64 + lane;
        int v = (i < nb) ? aux[i] : 0;
        int s = v;
        for (int off = 1; off < 64; off <<= 1) { int x = __shfl_up(s, off); if (lane >= off) s += x; }
        int tot = __shfl(s, 63);
        if (i < nb) aux[i] = run + s - v;
        run += tot;
    }
}

__global__ void scan3_k(const int* __restrict__ excl, const int* __restrict__ aux,
                        int* __restrict__ offs, int N, int E) {
    int i = blockIdx.x * 1024 + threadIdx.x;
    if (i < N) {
        offs[i] = excl[i] + aux[blockIdx.x];
    } else if (i == N) {
        offs[N] = E;
    }
}

// ---------------- GEMM + fused alpha dots ----------------
// H = X @ W (bf16 MFMA, fp32 acc); AS/AD = H . a_src/a_dst from fp32 accs.
// F32IN: X fp32 (convert during staging) else bf16.
template <int K, int DO, bool F32IN>
__global__ __launch_bounds__(256, 2) void gemm_k(const void* __restrict__ Xv,
                                                 const u16* __restrict__ Wf,
                                                 void* __restrict__ Hv,
                                                 const float* __restrict__ a_src,
                                                 const float* __restrict__ a_dst,
                                                 float* __restrict__ AS,
                                                 float* __restrict__ AD, int nrow) {
    constexpr int BM = 128, BK = 64;
    __shared__ alignas(16) u16 At[BM * BK];  // 16 KB bf16, XOR-swizzled 16B units
    const int tid = threadIdx.x;
    const int wave = tid >> 6, lane = tid & 63;
    const int quad = lane >> 4, l16 = lane & 15;
    const int row0 = blockIdx.x * BM;

    floatx4 acc[2][DO / 16];
#pragma unroll
    for (int a = 0; a < 2; a++)
#pragma unroll
        for (int b = 0; b < DO / 16; b++) acc[a][b] = floatx4{0.f, 0.f, 0.f, 0.f};

    for (int kt = 0; kt < K / BK; ++kt) {
        __syncthreads();
#pragma unroll
        for (int i = 0; i < 4; ++i) {
            int seg = tid + i * 256;          // 1024 segments of 8 k-elements
            int r = seg >> 3, c = seg & 7;
            int gr = row0 + r;
            gr = gr < nrow ? gr : nrow - 1;   // clamp (pad rows discarded on store)
            if (F32IN) {
                const float* X = (const float*)Xv;
                float4 v0 = *(const float4*)(X + (size_t)gr * K + kt * BK + c * 8);
                float4 v1 = *(const float4*)(X + (size_t)gr * K + kt * BK + c * 8 + 4);
                int4 pk;
                pk.x = (int)cvt_pk_bf16(v0.x, v0.y);
                pk.y = (int)cvt_pk_bf16(v0.z, v0.w);
                pk.z = (int)cvt_pk_bf16(v1.x, v1.y);
                pk.w = (int)cvt_pk_bf16(v1.z, v1.w);
                *(int4*)(At + r * BK + (c ^ (r & 7)) * 8) = pk;
            } else {
                const u16* X = (const u16*)Xv;
                int4 v = *(const int4*)(X + (size_t)gr * K + kt * BK + c * 8);
                *(int4*)(At + r * BK + (c ^ (r & 7)) * 8) = v;
            }
        }
        __syncthreads();
#pragma unroll
        for (int ks = 0; ks < 2; ++ks) {
            short8 bfr[DO / 16];
            int kq = kt * 8 + ks * 4 + quad;
#pragma unroll
            for (int ct = 0; ct < DO / 16; ++ct)
                bfr[ct] = *(const short8*)(Wf + ((size_t)kq * DO + ct * 16 + l16) * 8);
#pragma unroll
            for (int rt = 0; rt < 2; ++rt) {
                int row = wave * 32 + rt * 16 + l16;
                int unit = (ks * 4 + quad) ^ (row & 7);
                short8 afr = *(const short8*)(At + row * BK + unit * 8);
#pragma unroll
                for (int ct = 0; ct < DO / 16; ++ct)
                    acc[rt][ct] =
                        __builtin_amdgcn_mfma_f32_16x16x32_bf16(afr, bfr[ct], acc[rt][ct], 0, 0, 0);
            }
        }
    }
    // Epilogue. C/D layout: col = ct*16 + l16, row = quad*4 + r  [m89/m91 verified].
    float asv[DO / 16], adv[DO / 16];
#pragma unroll
    for (int ct = 0; ct < DO / 16; ++ct) {
        asv[ct] = a_src[ct * 16 + l16];
        adv[ct] = a_dst[ct * 16 + l16];
    }
#pragma unroll
    for (int rt = 0; rt < 2; ++rt)
#pragma unroll
        for (int r = 0; r < 4; ++r) {
            int grow = row0 + wave * 32 + rt * 16 + quad * 4 + r;
            bool ok = grow < nrow;
            float ps = 0.f, pd = 0.f;
#pragma unroll
            for (int ct = 0; ct < DO / 16; ++ct) {
                float v = acc[rt][ct][r];
                ps = fmaf(v, asv[ct], ps);
                pd = fmaf(v, adv[ct], pd);
                if (ok) ((u16*)Hv)[(size_t)grow * DO + ct * 16 + l16] = f2bf(v);
            }
            // reduce over the 16-lane col group (xor bits 0-3 stay within quad)
#pragma unroll
            for (int o = 1; o < 16; o <<= 1) {
                ps += __shfl_xor(ps, o);
                pd += __shfl_xor(pd, o);
            }
            if (ok && l16 == 0) {
                AS[grow] = ps;
                AD[grow] = pd;
            }
        }
}

// ---------------- fused segment softmax + aggregate (one wave per dst node) ----------------
// Gather scheme: 16 lanes own one edge-row; a wave processes 4 edges per load
// instruction. Row = 256B (DO=128 bf16) or 128B (DO=64 bf16).
// HB: h rows bf16 (else fp32). OUTB: write bf16 packed (else fp32).
template <int DO, bool HB, bool OUTB>
__global__ __launch_bounds__(256) void agg_k(const void* __restrict__ Hv,
                                             const float* __restrict__ AS,
                                             const float* __restrict__ AD,
                                             const int* __restrict__ offs,
                                             const int* __restrict__ esrc,
                                             const float* __restrict__ bias,
                                             void* __restrict__ OUT, int N) {
    constexpr int NC = HB ? DO / 16 : 4;  // floats per lane slice (bf16: DO/16, fp32: 4)
    const int wave = threadIdx.x >> 6, lane = threadIdx.x & 63;
    const int sub = lane >> 4, l16 = lane & 15;
    const int d = blockIdx.x * 4 + wave;
    if (d >= N) return;
    const int o0 = offs[d];
    const int deg = offs[d + 1] - o0;  // real in-edges
    const int tot = deg + 1;           // + self loop
    const float ad = AD[d];

    float acc[NC];
#pragma unroll
    for (int c = 0; c < NC; ++c) acc[c] = 0.f;

    // gather one row-slice of row sl with weight wl
    auto gath = [&](float wl, int sl) {
        if (HB) {
            if (DO == 128) {
                uint4 hv = ((const uint4*)Hv)[(size_t)sl * 16 + l16];
                u32 p[4] = {hv.x, hv.y, hv.z, hv.w};
#pragma unroll
                for (int c = 0; c < 4; ++c) {
                    acc[2 * c] = fmaf(wl, bf2f((u16)p[c]), acc[2 * c]);
                    acc[2 * c + 1] = fmaf(wl, bf2f((u16)(p[c] >> 16)), acc[2 * c + 1]);
                }
            } else {
                uint2 hv = ((const uint2*)Hv)[(size_t)sl * 16 + l16];
                acc[0] = fmaf(wl, bf2f((u16)hv.x), acc[0]);
                acc[1] = fmaf(wl, bf2f((u16)(hv.x >> 16)), acc[1]);
                acc[2] = fmaf(wl, bf2f((u16)hv.y), acc[2]);
                acc[3] = fmaf(wl, bf2f((u16)(hv.y >> 16)), acc[3]);
            }
        } else {
            float4 hv = ((const float4*)Hv)[(size_t)sl * 16 + l16];
            acc[0] = fmaf(wl, hv.x, acc[0]);
            acc[1] = fmaf(wl, hv.y, acc[1]);
            acc[2] = fmaf(wl, hv.z, acc[2]);
            acc[3] = fmaf(wl, hv.w, acc[3]);
        }
    };
    // 4 edges starting at l: sub-group `sub` takes edge l+sub (w,s live in lane idx)
    auto quad = [&](float w, int s, int l, int lim) {
        int idx = l + sub;
        int cl = idx < lim ? idx : lim - 1;
        float wv = __shfl(w, cl);  // ds_bpermute, per-lane src index
        int sl = __shfl(s, cl);
        gath(idx < lim ? wv : 0.f, sl);
    };

    if (tot <= 64) {
        // ---- fast path: whole segment resident in one wave, single gather pass ----
        int s = (lane < deg) ? esrc[o0 + lane] : d;  // lane==deg -> self loop
        bool valid = lane < tot;
        float lg = AS[s] + ad;
        lg = lg > 0.f ? lg : lg * 0.2f;
        float lgv = valid ? lg : -1e30f;
        float m = lgv;
        for (int o = 32; o; o >>= 1) m = fmaxf(m, __shfl_xor(m, o));
        float e = valid ? __expf(lg - m) : 0.f;
        float sum = e;
        for (int o = 32; o; o >>= 1) sum += __shfl_xor(sum, o);
        float w = e * (1.f / sum);
        for (int l = 0; l < tot; l += 16) {
#pragma unroll
            for (int g = 0; g < 4; ++g)
                if (l + g * 4 < tot) quad(w, s, l + g * 4, tot);
        }
    } else {
        // ---- general path (deg > 63, rare at avg deg 16): 3-pass ----
        float mx = -1e30f;
        for (int i = lane; i < tot; i += 64) {
            int s = (i < deg) ? esrc[o0 + i] : d;
            float lg = AS[s] + ad;
            lg = lg > 0.f ? lg : lg * 0.2f;
            mx = fmaxf(mx, lg);
        }
        for (int o = 32; o; o >>= 1) mx = fmaxf(mx, __shfl_xor(mx, o));
        float sum = 0.f;
        for (int i = lane; i < tot; i += 64) {
            int s = (i < deg) ? esrc[o0 + i] : d;
            float lg = AS[s] + ad;
            lg = lg > 0.f ? lg : lg * 0.2f;
            sum += __expf(lg - mx);
        }
        for (int o = 32; o; o >>= 1) sum += __shfl_xor(sum, o);
        const float inv = 1.f / sum;
        for (int c0 = 0; c0 < tot; c0 += 64) {
            int i = c0 + lane;
            float w = 0.f;
            int s = d;
            if (i < tot) {
                s = (i < deg) ? esrc[o0 + i] : d;
                float lg = AS[s] + ad;
                lg = lg > 0.f ? lg : lg * 0.2f;
                w = __expf(lg - mx) * inv;
            }
            int cn = tot - c0;
            cn = cn < 64 ? cn : 64;
            for (int l = 0; l < cn; l += 16) {
#pragma unroll
                for (int g = 0; g < 4; ++g)
                    if (l + g * 4 < cn) quad(w, s, l + g * 4, cn);
            }
        }
    }

    // fold the 4 edge-subsets
#pragma unroll
    for (int c = 0; c < NC; ++c) {
        acc[c] += __shfl_xor(acc[c], 16);
        acc[c] += __shfl_xor(acc[c], 32);
    }

    // epilogue: + bias, leaky_relu(0.25), store (sub==0 lanes write their slice)
    if (sub == 0) {
        if (DO == 128) {
            u32 pk[4];
            float fv[8];
#pragma unroll
            for (int c = 0; c < 8; ++c) {
                float v = acc[c] + bias[l16 * 8 + c];
                fv[c] = v > 0.f ? v : v * 0.25f;
            }
            if (OUTB) {
#pragma unroll
                for (int c = 0; c < 4; ++c)
                    pk[c] = (u32)f2bf(fv[2 * c]) | ((u32)f2bf(fv[2 * c + 1]) << 16);
                ((uint4*)OUT)[(size_t)d * 16 + l16] = uint4{pk[0], pk[1], pk[2], pk[3]};
            } else {
                float4 o0v = float4{fv[0], fv[1], fv[2], fv[3]};
                float4 o1v = float4{fv[4], fv[5], fv[6], fv[7]};
                ((float4*)OUT)[(size_t)d * 32 + l16 * 2] = o0v;
                ((float4*)OUT)[(size_t)d * 32 + l16 * 2 + 1] = o1v;
            }
        } else {
            float4 v;
            v.x = acc[0] + bias[l16 * 4 + 0];
            v.y = acc[1] + bias[l16 * 4 + 1];
            v.z = acc[2] + bias[l16 * 4 + 2];
            v.w = acc[3] + bias[l16 * 4 + 3];
            v.x = v.x > 0.f ? v.x : v.x * 0.25f;
            v.y = v.y > 0.f ? v.y : v.y * 0.25f;
            v.z = v.z > 0.f ? v.z : v.z * 0.25f;
            v.w = v.w > 0.f ? v.w : v.w * 0.25f;
            if (OUTB) {
                u32 p0 = (u32)f2bf(v.x) | ((u32)f2bf(v.y) << 16);
                u32 p1 = (u32)f2bf(v.z) | ((u32)f2bf(v.w) << 16);
                ((uint2*)OUT)[(size_t)d * 16 + l16] = uint2{p0, p1};
            } else {
                ((float4*)OUT)[(size_t)d * 16 + l16] = v;
            }
        }
    }
}

// ---------------- launch ----------------

extern "C" void kernel_launch(void* const* d_in, const int* in_sizes, int n_in,
                              void* d_out, int out_size, void* d_ws, size_t ws_size,
                              hipStream_t stream) {
    const int N = in_sizes[0] / 512;  // 100000
    const int E = in_sizes[1] / 2;    // 1600000

    const float* data = (const float*)d_in[0];
    const int* adj = (const int*)d_in[1];
    const float* W1 = (const float*)d_in[2];
    const float* as1 = (const float*)d_in[3];
    const float* ad1 = (const float*)d_in[4];
    const float* b1 = (const float*)d_in[5];
    const float* W2 = (const float*)d_in[6];
    const float* as2 = (const float*)d_in[7];
    const float* ad2 = (const float*)d_in[8];
    const float* b2 = (const float*)d_in[9];
    const float* W3 = (const float*)d_in[10];
    const float* as3 = (const float*)d_in[11];
    const float* ad3 = (const float*)d_in[12];
    const float* b3 = (const float*)d_in[13];

    const int NBUCK = (N + 127) >> 7;     // 782
    const int SCN = NBUCK * B1;           // 200192
    const int TILE = (E + B1 - 1) / B1;   // 6250

    // ---- workspace carve + budget check ----
    char* ws = (char*)d_ws;
    size_t need = 0;
    auto carve = [&](size_t bytes) {
        void* p = (void*)(ws + need);
        need += (bytes + 255) & ~(size_t)255;
        return p;
    };
    int* esrc = (int*)carve((size_t)E * 4);
    int* offs = (int*)carve((size_t)(N + 1) * 4);
    int* aux = (int*)carve(1024);
    float* AS = (float*)carve((size_t)N * 4);
    float* AD = (float*)carve((size_t)N * 4);
    u64* ebuf = (u64*)carve((size_t)E * 8);
    int* M = (int*)carve((size_t)SCN * 4);
    int* Mex = (int*)carve((size_t)SCN * 4);
    int* Ms = (int*)carve((size_t)(SCN + 2) * 4);
    u16* Hb = (u16*)carve((size_t)N * 128 * 2);  // bf16 h (all 3 layers; L3 uses 64 cols)
    u16* x1 = (u16*)carve((size_t)N * 128 * 2);  // bf16 next-layer input
    u16* x2 = x1;                                // x1 dead after layer-2 GEMM
    u16* Wf1 = (u16*)carve(512 * 128 * 2);
    u16* Wf2 = (u16*)carve(128 * 128 * 2);
    u16* Wf3 = (u16*)carve(128 * 64 * 2);

    if (need > ws_size) {
        // Diagnostic signature: absmax == ref absmax (0.2373) => ws too small.
        zero_out_k<<<(out_size + 255) / 256, 256, 0, stream>>>((float*)d_out, out_size);
        return;
    }

    const int* srcl = adj;
    const int* dstl = adj + E;

    const int gblk = (N + 127) / 128;
    const int nblk = (N + 3) / 4;

    // ---- weight prepack ----
    {
        const int total = 512 * 128 + 128 * 128 + 128 * 64;
        prepack3_k<<<(total + 255) / 256, 256, 0, stream>>>(W1, Wf1, W2, Wf2, W3, Wf3);
    }

    // ---- CSR build: bucket sort, no global atomics ----
    bucketA_k<<<B1, 256, 0, stream>>>(dstl, M, E, N, NBUCK, TILE);
    int nb1 = (SCN + 1023) / 1024;  // 196 <= 256 (scan2 capacity)
    scan1_k<<<nb1, 1024, 0, stream>>>(M, Mex, aux, SCN);
    scan2_k<<<1, 64, 0, stream>>>(aux, nb1);
    scan3_k<<<nb1, 1024, 0, stream>>>(Mex, aux, Ms, SCN, E);  // also Ms[SCN]=E
    bucketB_k<<<B1, 256, 0, stream>>>(srcl, dstl, Ms, ebuf, E, N, NBUCK, TILE);
    bucketC_k<<<NBUCK, 256, 0, stream>>>(ebuf, Ms, offs, esrc, E, N, NBUCK);

    // ---- layer 1 ----
    gemm_k<512, 128, true><<<gblk, 256, 0, stream>>>(data, Wf1, Hb, as1, ad1, AS, AD, N);
    agg_k<128, true, true><<<nblk, 256, 0, stream>>>(Hb, AS, AD, offs, esrc, b1, x1, N);
    // ---- layer 2 ----
    gemm_k<128, 128, false><<<gblk, 256, 0, stream>>>(x1, Wf2, Hb, as2, ad2, AS, AD, N);
    agg_k<128, true, true><<<nblk, 256, 0, stream>>>(Hb, AS, AD, offs, esrc, b2, x2, N);
    // ---- layer 3: h3 bf16 (128B rows) ----
    gemm_k<128, 64, false><<<gblk, 256, 0, stream>>>(x2, Wf3, Hb, as3, ad3, AS, AD, N);
    agg_k<64, true, false><<<nblk, 256, 0, stream>>>(Hb, AS, AD, offs, esrc, b3, d_out, N);
}